// Round 6
// baseline (104.206 us; speedup 1.0000x reference)
//
#include <hip/hip_runtime.h>
#include <hip/hip_cooperative_groups.h>

namespace cg = cooperative_groups;

#define B_ 64
#define N_ 900
#define C_ 16
#define NCHAR_ 75
#define L_ 8

// Single cooperative dispatch, R0 geometry: 900 blocks x 64 threads, thread =
// one bn, all lanes active, plain float4-pair string loads (32B/lane/char,
// 2KB contiguous per wave -- the proven ~5.5 TB/s pattern).
// Tail: per-block segmented wave-min -> plain store to slot[blockIdx] (no
// init needed: every slot written every call) -> grid.sync() -> blocks 0..63
// reduce their image's <=16 slots and write out[b]. No atomics, no fill.
__global__ __launch_bounds__(64) void fused_kernel(
    const float* __restrict__ logits,   // [B,N,C]
    const float* __restrict__ boxes,    // [B,N,8]
    const float* __restrict__ ps,       // [B,NCHAR,N,L]
    const float* __restrict__ tgt,      // [B,4]
    const int*   __restrict__ ptype,    // [B]
    const int*   __restrict__ lps,      // [B,L]
    ulonglong2* __restrict__ slot,      // ws: [900] {p0 for b0, p1 for b1}
    int* __restrict__ out)              // [B,1]
{
    int bn = blockIdx.x * 64 + threadIdx.x;   // 900*64 = 57600 exact
    int b  = bn / N_;
    int n  = bn - b * N_;

    // ---------- string CE: lse over 75 chars per l, minus target logit ----------
    int tl[L_];
    {
        const int4* lp4 = (const int4*)(lps + b * L_);
        int4 q0 = lp4[0], q1 = lp4[1];
        tl[0]=q0.x; tl[1]=q0.y; tl[2]=q0.z; tl[3]=q0.w;
        tl[4]=q1.x; tl[5]=q1.y; tl[6]=q1.z; tl[7]=q1.w;
    }
    float s[L_], tv[L_];
    #pragma unroll
    for (int l = 0; l < L_; ++l) { s[l] = 0.0f; tv[l] = 0.0f; }

    const float* base = ps + ((size_t)b * NCHAR_ * N_ + n) * L_;
    #pragma unroll 5
    for (int c = 0; c < NCHAR_; ++c) {
        const float4* p4 = (const float4*)(base + (size_t)c * (N_ * L_));
        float4 a = p4[0];
        float4 d = p4[1];
        s[0] += __expf(a.x); tv[0] = (c == tl[0]) ? a.x : tv[0];
        s[1] += __expf(a.y); tv[1] = (c == tl[1]) ? a.y : tv[1];
        s[2] += __expf(a.z); tv[2] = (c == tl[2]) ? a.z : tv[2];
        s[3] += __expf(a.w); tv[3] = (c == tl[3]) ? a.w : tv[3];
        s[4] += __expf(d.x); tv[4] = (c == tl[4]) ? d.x : tv[4];
        s[5] += __expf(d.y); tv[5] = (c == tl[5]) ? d.y : tv[5];
        s[6] += __expf(d.z); tv[6] = (c == tl[6]) ? d.z : tv[6];
        s[7] += __expf(d.w); tv[7] = (c == tl[7]) ? d.w : tv[7];
    }
    float ce = 0.0f;
    #pragma unroll
    for (int l = 0; l < L_; ++l) ce += __logf(s[l]) - tv[l];
    float cost_string = ce * (1.0f / L_);

    // ---------- class cost: -softmax(logits)[plate_type] ----------
    float x[C_];
    {
        const float4* lg = (const float4*)(logits + (size_t)bn * C_);
        float4 q0 = lg[0], q1 = lg[1], q2 = lg[2], q3 = lg[3];
        x[0]=q0.x; x[1]=q0.y; x[2]=q0.z; x[3]=q0.w;
        x[4]=q1.x; x[5]=q1.y; x[6]=q1.z; x[7]=q1.w;
        x[8]=q2.x; x[9]=q2.y; x[10]=q2.z; x[11]=q2.w;
        x[12]=q3.x; x[13]=q3.y; x[14]=q3.z; x[15]=q3.w;
    }
    int tcls = ptype[b];
    float m = x[0];
    #pragma unroll
    for (int i = 1; i < C_; ++i) m = fmaxf(m, x[i]);
    float se = 0.0f, xt = 0.0f;
    #pragma unroll
    for (int i = 0; i < C_; ++i) {
        se += __expf(x[i] - m);
        xt = (i == tcls) ? x[i] : xt;
    }
    float cost_class = -__expf(xt - m) / se;

    // ---------- bbox: vertices -> xyxy, L1, GIoU ----------
    float4 tb = *(const float4*)(tgt + b * 4);
    const float4* bx = (const float4*)(boxes + (size_t)bn * 8);
    float4 w0 = bx[0], w1 = bx[1];
    float px1 = fminf(fminf(w0.x, w0.z), fminf(w1.x, w1.z));
    float py1 = fminf(fminf(w0.y, w0.w), fminf(w1.y, w1.w));
    float px2 = fmaxf(fmaxf(w0.x, w0.z), fmaxf(w1.x, w1.z));
    float py2 = fmaxf(fmaxf(w0.y, w0.w), fmaxf(w1.y, w1.w));

    float cost_bbox = fabsf(px1 - tb.x) + fabsf(py1 - tb.y)
                    + fabsf(px2 - tb.z) + fabsf(py2 - tb.w);

    float ltx = fmaxf(px1, tb.x), lty = fmaxf(py1, tb.y);
    float rbx = fminf(px2, tb.z), rby = fminf(py2, tb.w);
    float iw = fmaxf(rbx - ltx, 0.0f), ih = fmaxf(rby - lty, 0.0f);
    float inter = iw * ih;
    float area_p = (px2 - px1) * (py2 - py1);
    float area_t = (tb.z - tb.x) * (tb.w - tb.y);
    float uni = area_p + area_t - inter;
    float iou = inter / uni;
    float cx1 = fminf(px1, tb.x), cy1 = fminf(py1, tb.y);
    float cx2 = fmaxf(px2, tb.z), cy2 = fmaxf(py2, tb.w);
    float cw = fmaxf(cx2 - cx1, 0.0f), ch = fmaxf(cy2 - cy1, 0.0f);
    float area_c = cw * ch;
    float giou = iou - (area_c - uni) / area_c;

    float cost = cost_class + 5.0f * cost_bbox - 2.0f * giou + 10.0f * cost_string;

    // ---------- packed (orderable cost << 32) | n : min == argmin, first-idx ----------
    unsigned u = __float_as_uint(cost);
    u = (u & 0x80000000u) ? ~u : (u | 0x80000000u);
    unsigned long long pk = ((unsigned long long)u << 32) | (unsigned)n;

    // ---------- segmented wave min (block may span 2 images) ----------
    int b0 = (blockIdx.x * 64) / N_;          // image of lane 0
    unsigned long long p0 = (b == b0) ? pk : ~0ull;
    unsigned long long p1 = (b != b0) ? pk : ~0ull;
    #pragma unroll
    for (int off = 1; off < 64; off <<= 1) {
        unsigned long long q0 = __shfl_xor(p0, off);
        unsigned long long q1 = __shfl_xor(p1, off);
        p0 = (q0 < p0) ? q0 : p0;
        p1 = (q1 < p1) ? q1 : p1;
    }
    if (threadIdx.x == 0) {
        ulonglong2 v; v.x = p0; v.y = p1;
        slot[blockIdx.x] = v;                 // plain store, no init needed
    }

    cg::this_grid().sync();

    // ---------- blocks 0..63: reduce image b's <=16 slots ----------
    if (blockIdx.x < B_) {
        int bb = blockIdx.x;
        int g0 = (N_ * bb) / 64;
        int g1 = (N_ * (bb + 1) - 1) / 64;
        int t  = threadIdx.x;
        unsigned long long v = ~0ull;
        int g = g0 + t;
        if (g <= g1) {
            ulonglong2 sl = slot[g];
            int gb0 = (g * 64) / N_;
            v = (gb0 == bb) ? sl.x : sl.y;
        }
        #pragma unroll
        for (int off = 1; off < 64; off <<= 1) {
            unsigned long long q = __shfl_xor(v, off);
            v = (q < v) ? q : v;
        }
        if (t == 0) out[bb] = (int)(v & 0xFFFFFFFFull);
    }
}

extern "C" void kernel_launch(void* const* d_in, const int* in_sizes, int n_in,
                              void* d_out, int out_size, void* d_ws, size_t ws_size,
                              hipStream_t stream) {
    const float* logits = (const float*)d_in[0];   // pred_logits [B,N,C]
    const float* boxes  = (const float*)d_in[1];   // pred_boxes  [B,N,8]
    const float* ps     = (const float*)d_in[2];   // pred_string_logits [B,75,N,8]
    const float* tgt    = (const float*)d_in[3];   // tgt_bboxes [B,4]
    const int*   ptype  = (const int*)d_in[4];     // plate_type [B]
    const int*   lps    = (const int*)d_in[5];     // lps [B,L]

    ulonglong2* slot = (ulonglong2*)d_ws;          // 900 * 16B = 14.4 KB
    int* out = (int*)d_out;

    void* args[] = {
        (void*)&logits, (void*)&boxes, (void*)&ps, (void*)&tgt,
        (void*)&ptype, (void*)&lps, (void*)&slot, (void*)&out
    };
    hipLaunchCooperativeKernel((const void*)fused_kernel,
                               dim3(N_), dim3(64), args, 0, stream);
}

// Round 7
// 29.000 us; speedup vs baseline: 3.5933x; 3.5933x over previous
//
#include <hip/hip_runtime.h>

#define B_ 64
#define N_ 900
#define C_ 16
#define NCHAR_ 75
#define L_ 8

// K1: R0 geometry (proven ~5.5 TB/s): 900 blocks x 64 threads (1 wave),
// thread = one bn, plain float4-pair string loads (32B/lane/char, 2KB
// contiguous per wave). Tail: segmented wave-min on packed
// (orderable_cost<<32 | n) u64 and ONE plain ulonglong2 store per block.
// No cost array, no atomics, no workspace init (every slot written per call).
__global__ __launch_bounds__(64) void cost_kernel(
    const float* __restrict__ logits,   // [B,N,C]
    const float* __restrict__ boxes,    // [B,N,8]
    const float* __restrict__ ps,       // [B,NCHAR,N,L]
    const float* __restrict__ tgt,      // [B,4]
    const int*   __restrict__ ptype,    // [B]
    const int*   __restrict__ lps,      // [B,L]
    ulonglong2* __restrict__ slot)      // ws: [900] {min for b0, min for b1}
{
    int bn = blockIdx.x * 64 + threadIdx.x;   // 900*64 = 57600 exact
    int b  = bn / N_;
    int n  = bn - b * N_;

    // ---------- string CE: lse over 75 chars per l, minus target logit ----------
    int tl[L_];
    {
        const int4* lp4 = (const int4*)(lps + b * L_);
        int4 q0 = lp4[0], q1 = lp4[1];
        tl[0]=q0.x; tl[1]=q0.y; tl[2]=q0.z; tl[3]=q0.w;
        tl[4]=q1.x; tl[5]=q1.y; tl[6]=q1.z; tl[7]=q1.w;
    }
    float s[L_], tv[L_];
    #pragma unroll
    for (int l = 0; l < L_; ++l) { s[l] = 0.0f; tv[l] = 0.0f; }

    const float* base = ps + ((size_t)b * NCHAR_ * N_ + n) * L_;
    #pragma unroll 5
    for (int c = 0; c < NCHAR_; ++c) {
        const float4* p4 = (const float4*)(base + (size_t)c * (N_ * L_));
        float4 a = p4[0];
        float4 d = p4[1];
        s[0] += __expf(a.x); tv[0] = (c == tl[0]) ? a.x : tv[0];
        s[1] += __expf(a.y); tv[1] = (c == tl[1]) ? a.y : tv[1];
        s[2] += __expf(a.z); tv[2] = (c == tl[2]) ? a.z : tv[2];
        s[3] += __expf(a.w); tv[3] = (c == tl[3]) ? a.w : tv[3];
        s[4] += __expf(d.x); tv[4] = (c == tl[4]) ? d.x : tv[4];
        s[5] += __expf(d.y); tv[5] = (c == tl[5]) ? d.y : tv[5];
        s[6] += __expf(d.z); tv[6] = (c == tl[6]) ? d.z : tv[6];
        s[7] += __expf(d.w); tv[7] = (c == tl[7]) ? d.w : tv[7];
    }
    float ce = 0.0f;
    #pragma unroll
    for (int l = 0; l < L_; ++l) ce += __logf(s[l]) - tv[l];
    float cost_string = ce * (1.0f / L_);

    // ---------- class cost: -softmax(logits)[plate_type] ----------
    float x[C_];
    {
        const float4* lg = (const float4*)(logits + (size_t)bn * C_);
        float4 q0 = lg[0], q1 = lg[1], q2 = lg[2], q3 = lg[3];
        x[0]=q0.x; x[1]=q0.y; x[2]=q0.z; x[3]=q0.w;
        x[4]=q1.x; x[5]=q1.y; x[6]=q1.z; x[7]=q1.w;
        x[8]=q2.x; x[9]=q2.y; x[10]=q2.z; x[11]=q2.w;
        x[12]=q3.x; x[13]=q3.y; x[14]=q3.z; x[15]=q3.w;
    }
    int tcls = ptype[b];
    float m = x[0];
    #pragma unroll
    for (int i = 1; i < C_; ++i) m = fmaxf(m, x[i]);
    float se = 0.0f, xt = 0.0f;
    #pragma unroll
    for (int i = 0; i < C_; ++i) {
        se += __expf(x[i] - m);
        xt = (i == tcls) ? x[i] : xt;
    }
    float cost_class = -__expf(xt - m) / se;

    // ---------- bbox: vertices -> xyxy, L1, GIoU ----------
    float4 tb = *(const float4*)(tgt + b * 4);
    const float4* bx = (const float4*)(boxes + (size_t)bn * 8);
    float4 w0 = bx[0], w1 = bx[1];
    float px1 = fminf(fminf(w0.x, w0.z), fminf(w1.x, w1.z));
    float py1 = fminf(fminf(w0.y, w0.w), fminf(w1.y, w1.w));
    float px2 = fmaxf(fmaxf(w0.x, w0.z), fmaxf(w1.x, w1.z));
    float py2 = fmaxf(fmaxf(w0.y, w0.w), fmaxf(w1.y, w1.w));

    float cost_bbox = fabsf(px1 - tb.x) + fabsf(py1 - tb.y)
                    + fabsf(px2 - tb.z) + fabsf(py2 - tb.w);

    float ltx = fmaxf(px1, tb.x), lty = fmaxf(py1, tb.y);
    float rbx = fminf(px2, tb.z), rby = fminf(py2, tb.w);
    float iw = fmaxf(rbx - ltx, 0.0f), ih = fmaxf(rby - lty, 0.0f);
    float inter = iw * ih;
    float area_p = (px2 - px1) * (py2 - py1);
    float area_t = (tb.z - tb.x) * (tb.w - tb.y);
    float uni = area_p + area_t - inter;
    float iou = inter / uni;
    float cx1 = fminf(px1, tb.x), cy1 = fminf(py1, tb.y);
    float cx2 = fmaxf(px2, tb.z), cy2 = fmaxf(py2, tb.w);
    float cw = fmaxf(cx2 - cx1, 0.0f), ch = fmaxf(cy2 - cy1, 0.0f);
    float area_c = cw * ch;
    float giou = iou - (area_c - uni) / area_c;

    float cost = cost_class + 5.0f * cost_bbox - 2.0f * giou + 10.0f * cost_string;

    // ---------- packed (orderable cost << 32) | n : min == argmin, first-idx ----------
    unsigned u = __float_as_uint(cost);
    u = (u & 0x80000000u) ? ~u : (u | 0x80000000u);
    unsigned long long pk = ((unsigned long long)u << 32) | (unsigned)n;

    // ---------- segmented wave min (block may span 2 images) ----------
    int b0 = (blockIdx.x * 64) / N_;          // image of lane 0
    unsigned long long p0 = (b == b0) ? pk : ~0ull;
    unsigned long long p1 = (b != b0) ? pk : ~0ull;
    #pragma unroll
    for (int off = 1; off < 64; off <<= 1) {
        unsigned long long q0 = __shfl_xor(p0, off);
        unsigned long long q1 = __shfl_xor(p1, off);
        p0 = (q0 < p0) ? q0 : p0;
        p1 = (q1 < p1) ? q1 : p1;
    }
    if (threadIdx.x == 0) {
        ulonglong2 v; v.x = p0; v.y = p1;
        slot[blockIdx.x] = v;                 // plain store, no init needed
    }
}

// K2: 64 blocks x 64 threads; block bb reduces its image's <=16 slots
// (verified slot->image mapping from R6) and writes out[bb].
__global__ __launch_bounds__(64) void argmin_kernel(
    const ulonglong2* __restrict__ slot, int* __restrict__ out)
{
    int bb = blockIdx.x;
    int g0 = (N_ * bb) / 64;
    int g1 = (N_ * (bb + 1) - 1) / 64;
    int t  = threadIdx.x;
    unsigned long long v = ~0ull;
    int g = g0 + t;
    if (g <= g1) {
        ulonglong2 sl = slot[g];
        int gb0 = (g * 64) / N_;
        v = (gb0 == bb) ? sl.x : sl.y;
    }
    #pragma unroll
    for (int off = 1; off < 64; off <<= 1) {
        unsigned long long q = __shfl_xor(v, off);
        v = (q < v) ? q : v;
    }
    if (t == 0) out[bb] = (int)(v & 0xFFFFFFFFull);
}

extern "C" void kernel_launch(void* const* d_in, const int* in_sizes, int n_in,
                              void* d_out, int out_size, void* d_ws, size_t ws_size,
                              hipStream_t stream) {
    const float* logits = (const float*)d_in[0];   // pred_logits [B,N,C]
    const float* boxes  = (const float*)d_in[1];   // pred_boxes  [B,N,8]
    const float* ps     = (const float*)d_in[2];   // pred_string_logits [B,75,N,8]
    const float* tgt    = (const float*)d_in[3];   // tgt_bboxes [B,4]
    const int*   ptype  = (const int*)d_in[4];     // plate_type [B]
    const int*   lps    = (const int*)d_in[5];     // lps [B,L]

    ulonglong2* slot = (ulonglong2*)d_ws;          // 900 * 16B = 14.4 KB
    int* out = (int*)d_out;

    cost_kernel<<<N_, 64, 0, stream>>>(logits, boxes, ps, tgt, ptype, lps, slot);
    argmin_kernel<<<B_, 64, 0, stream>>>(slot, out);
}

// Round 8
// 28.416 us; speedup vs baseline: 3.6671x; 1.0205x over previous
//
#include <hip/hip_runtime.h>

#define B_ 64
#define N_ 900
#define C_ 16
#define NCHAR_ 75
#define L_ 8

// K1: R7 structure, but the 75-char LSE loop is split across 2 waves per
// 64-bn group (block = 128 thr): wave0 chars [0,38), wave1 [38,75). Both
// waves issue 32B/lane float4-pair loads -> 2x in-flight bytes/CU vs R7
// (7 waves/CU instead of 3.5). Partials combine by addition (s: partial
// sums; tv: target char lies in exactly one range, other half is 0) via
// conflict-free [8][64] LDS. Wave0 runs class/bbox/argmin tail and stores
// one ulonglong2 slot per block (no ws init, no atomics).
__global__ __launch_bounds__(128) void cost_kernel(
    const float* __restrict__ logits,   // [B,N,C]
    const float* __restrict__ boxes,    // [B,N,8]
    const float* __restrict__ ps,       // [B,NCHAR,N,L]
    const float* __restrict__ tgt,      // [B,4]
    const int*   __restrict__ ptype,    // [B]
    const int*   __restrict__ lps,      // [B,L]
    ulonglong2* __restrict__ slot)      // ws: [900] {min for b0, min for b1}
{
    int lane = threadIdx.x & 63;
    int half = threadIdx.x >> 6;              // 0: chars 0..37, 1: 38..74
    int bn = blockIdx.x * 64 + lane;          // 900 blocks x 64 bn
    int b  = bn / N_;
    int n  = bn - b * N_;

    // ---------- string CE partials over this wave's char range ----------
    int tl[L_];
    {
        const int4* lp4 = (const int4*)(lps + b * L_);
        int4 q0 = lp4[0], q1 = lp4[1];
        tl[0]=q0.x; tl[1]=q0.y; tl[2]=q0.z; tl[3]=q0.w;
        tl[4]=q1.x; tl[5]=q1.y; tl[6]=q1.z; tl[7]=q1.w;
    }
    float s[L_], tv[L_];
    #pragma unroll
    for (int l = 0; l < L_; ++l) { s[l] = 0.0f; tv[l] = 0.0f; }

    const float* base = ps + ((size_t)b * NCHAR_ * N_ + n) * L_;
    int c0 = half ? 38 : 0;
    int c1 = half ? 75 : 38;
    #pragma unroll 2
    for (int c = c0; c < c1; ++c) {
        const float4* p4 = (const float4*)(base + (size_t)c * (N_ * L_));
        float4 a = p4[0];
        float4 d = p4[1];
        s[0] += __expf(a.x); tv[0] = (c == tl[0]) ? a.x : tv[0];
        s[1] += __expf(a.y); tv[1] = (c == tl[1]) ? a.y : tv[1];
        s[2] += __expf(a.z); tv[2] = (c == tl[2]) ? a.z : tv[2];
        s[3] += __expf(a.w); tv[3] = (c == tl[3]) ? a.w : tv[3];
        s[4] += __expf(d.x); tv[4] = (c == tl[4]) ? d.x : tv[4];
        s[5] += __expf(d.y); tv[5] = (c == tl[5]) ? d.y : tv[5];
        s[6] += __expf(d.z); tv[6] = (c == tl[6]) ? d.z : tv[6];
        s[7] += __expf(d.w); tv[7] = (c == tl[7]) ? d.w : tv[7];
    }

    // ---------- combine wave1 partials into wave0 via LDS ----------
    __shared__ float sh_s[L_][64];
    __shared__ float sh_tv[L_][64];
    if (half) {
        #pragma unroll
        for (int l = 0; l < L_; ++l) { sh_s[l][lane] = s[l]; sh_tv[l][lane] = tv[l]; }
    }
    __syncthreads();
    if (half) return;                          // no barriers after this point
    #pragma unroll
    for (int l = 0; l < L_; ++l) { s[l] += sh_s[l][lane]; tv[l] += sh_tv[l][lane]; }

    float ce = 0.0f;
    #pragma unroll
    for (int l = 0; l < L_; ++l) ce += __logf(s[l]) - tv[l];
    float cost_string = ce * (1.0f / L_);

    // ---------- class cost: -softmax(logits)[plate_type] ----------
    float x[C_];
    {
        const float4* lg = (const float4*)(logits + (size_t)bn * C_);
        float4 q0 = lg[0], q1 = lg[1], q2 = lg[2], q3 = lg[3];
        x[0]=q0.x; x[1]=q0.y; x[2]=q0.z; x[3]=q0.w;
        x[4]=q1.x; x[5]=q1.y; x[6]=q1.z; x[7]=q1.w;
        x[8]=q2.x; x[9]=q2.y; x[10]=q2.z; x[11]=q2.w;
        x[12]=q3.x; x[13]=q3.y; x[14]=q3.z; x[15]=q3.w;
    }
    int tcls = ptype[b];
    float m = x[0];
    #pragma unroll
    for (int i = 1; i < C_; ++i) m = fmaxf(m, x[i]);
    float se = 0.0f, xt = 0.0f;
    #pragma unroll
    for (int i = 0; i < C_; ++i) {
        se += __expf(x[i] - m);
        xt = (i == tcls) ? x[i] : xt;
    }
    float cost_class = -__expf(xt - m) / se;

    // ---------- bbox: vertices -> xyxy, L1, GIoU ----------
    float4 tb = *(const float4*)(tgt + b * 4);
    const float4* bx = (const float4*)(boxes + (size_t)bn * 8);
    float4 w0 = bx[0], w1 = bx[1];
    float px1 = fminf(fminf(w0.x, w0.z), fminf(w1.x, w1.z));
    float py1 = fminf(fminf(w0.y, w0.w), fminf(w1.y, w1.w));
    float px2 = fmaxf(fmaxf(w0.x, w0.z), fmaxf(w1.x, w1.z));
    float py2 = fmaxf(fmaxf(w0.y, w0.w), fmaxf(w1.y, w1.w));

    float cost_bbox = fabsf(px1 - tb.x) + fabsf(py1 - tb.y)
                    + fabsf(px2 - tb.z) + fabsf(py2 - tb.w);

    float ltx = fmaxf(px1, tb.x), lty = fmaxf(py1, tb.y);
    float rbx = fminf(px2, tb.z), rby = fminf(py2, tb.w);
    float iw = fmaxf(rbx - ltx, 0.0f), ih = fmaxf(rby - lty, 0.0f);
    float inter = iw * ih;
    float area_p = (px2 - px1) * (py2 - py1);
    float area_t = (tb.z - tb.x) * (tb.w - tb.y);
    float uni = area_p + area_t - inter;
    float iou = inter / uni;
    float cx1 = fminf(px1, tb.x), cy1 = fminf(py1, tb.y);
    float cx2 = fmaxf(px2, tb.z), cy2 = fmaxf(py2, tb.w);
    float cw = fmaxf(cx2 - cx1, 0.0f), ch = fmaxf(cy2 - cy1, 0.0f);
    float area_c = cw * ch;
    float giou = iou - (area_c - uni) / area_c;

    float cost = cost_class + 5.0f * cost_bbox - 2.0f * giou + 10.0f * cost_string;

    // ---------- packed (orderable cost << 32) | n ----------
    unsigned u = __float_as_uint(cost);
    u = (u & 0x80000000u) ? ~u : (u | 0x80000000u);
    unsigned long long pk = ((unsigned long long)u << 32) | (unsigned)n;

    // ---------- segmented wave min (block's 64 bn may span 2 images) ----------
    int b0 = (blockIdx.x * 64) / N_;          // image of lane 0
    unsigned long long p0 = (b == b0) ? pk : ~0ull;
    unsigned long long p1 = (b != b0) ? pk : ~0ull;
    #pragma unroll
    for (int off = 1; off < 64; off <<= 1) {
        unsigned long long q0 = __shfl_xor(p0, off);
        unsigned long long q1 = __shfl_xor(p1, off);
        p0 = (q0 < p0) ? q0 : p0;
        p1 = (q1 < p1) ? q1 : p1;
    }
    if (lane == 0) {
        ulonglong2 v; v.x = p0; v.y = p1;
        slot[blockIdx.x] = v;                 // plain store, no init needed
    }
}

// K2: 64 blocks x 64 threads; block bb reduces its image's <=16 slots.
__global__ __launch_bounds__(64) void argmin_kernel(
    const ulonglong2* __restrict__ slot, int* __restrict__ out)
{
    int bb = blockIdx.x;
    int g0 = (N_ * bb) / 64;
    int g1 = (N_ * (bb + 1) - 1) / 64;
    int t  = threadIdx.x;
    unsigned long long v = ~0ull;
    int g = g0 + t;
    if (g <= g1) {
        ulonglong2 sl = slot[g];
        int gb0 = (g * 64) / N_;
        v = (gb0 == bb) ? sl.x : sl.y;
    }
    #pragma unroll
    for (int off = 1; off < 64; off <<= 1) {
        unsigned long long q = __shfl_xor(v, off);
        v = (q < v) ? q : v;
    }
    if (t == 0) out[bb] = (int)(v & 0xFFFFFFFFull);
}

extern "C" void kernel_launch(void* const* d_in, const int* in_sizes, int n_in,
                              void* d_out, int out_size, void* d_ws, size_t ws_size,
                              hipStream_t stream) {
    const float* logits = (const float*)d_in[0];   // pred_logits [B,N,C]
    const float* boxes  = (const float*)d_in[1];   // pred_boxes  [B,N,8]
    const float* ps     = (const float*)d_in[2];   // pred_string_logits [B,75,N,8]
    const float* tgt    = (const float*)d_in[3];   // tgt_bboxes [B,4]
    const int*   ptype  = (const int*)d_in[4];     // plate_type [B]
    const int*   lps    = (const int*)d_in[5];     // lps [B,L]

    ulonglong2* slot = (ulonglong2*)d_ws;          // 900 * 16B = 14.4 KB
    int* out = (int*)d_out;

    cost_kernel<<<N_, 128, 0, stream>>>(logits, boxes, ps, tgt, ptype, lps, slot);
    argmin_kernel<<<B_, 64, 0, stream>>>(slot, out);
}